// Round 13
// baseline (428.332 us; speedup 1.0000x reference)
//
#include <hip/hip_runtime.h>

typedef __bf16 bf16_t;
typedef __bf16 bf16x4 __attribute__((ext_vector_type(4)));
typedef __bf16 bf16x8 __attribute__((ext_vector_type(8)));
typedef float f32x4 __attribute__((ext_vector_type(4)));

#define NL 3
#define HD 128
#define ROWS 64
#define SSTR 144         // s_sig stride: 128 data + x(128..135) + [1,0..0](136..143) for bias-fold
#define RSTR 136         // s_r stride: 128 data + x(128..135)
#define THREADS 512
#define BATCH 262144
#define NBLK (BATCH / ROWS)

// ws layout (bf16 elems): MFMA fragment order; U sections have bias at k==8 (gates z,g,r + Sw)
#define SW_OFF 0                 // [ct=8][lane=64][j=8]                       = 4096
#define U_OFF  4096              // [l=3][g=4][ct=8][lane=64][j=8]             = 49152
#define W_OFF  53248             // [l=3][g=4][ct=8][kc=4][lane=64][j=8]       = 196608
#define WS_ELEMS 249856

#define MFMA(a, b, c) __builtin_amdgcn_mfma_f32_16x16x32_bf16((a), (b), (c), 0, 0, 0)

#define LOG2E 1.4426950408889634f
__device__ __forceinline__ float sigm(float v) {
    return __builtin_amdgcn_rcpf(1.f + __builtin_amdgcn_exp2f(-LOG2E * v));
}
__device__ __forceinline__ float sigmn(float v) {  // 1 - sigm(v)
    return __builtin_amdgcn_rcpf(1.f + __builtin_amdgcn_exp2f(LOG2E * v));
}
__device__ __forceinline__ float tanh_f(float v) {
    return 1.f - 2.f * __builtin_amdgcn_rcpf(__builtin_amdgcn_exp2f((2.f * LOG2E) * v) + 1.f);
}

// ---------------- prep: swizzle f32 weights (+ biases at k==8) into bf16 fragment order -------
__global__ void dgm_prep(const float* __restrict__ SwW, const float* __restrict__ Swb,
                         const float* __restrict__ Uz, const float* __restrict__ Wz, const float* __restrict__ Bz,
                         const float* __restrict__ Ug, const float* __restrict__ Wg, const float* __restrict__ Bg,
                         const float* __restrict__ Ur, const float* __restrict__ Wr, const float* __restrict__ Br,
                         const float* __restrict__ Uh, const float* __restrict__ Wh,
                         bf16_t* __restrict__ ws) {
    int idx = blockIdx.x * 256 + threadIdx.x;
    if (idx >= WS_ELEMS) return;
    const float* Us[4] = {Uz, Ug, Ur, Uh};
    const float* Wm[4] = {Wz, Wg, Wr, Wh};
    if (idx < U_OFF) {
        int ct = idx >> 9, rem = idx & 511, lane = rem >> 3, j = rem & 7;
        int q = lane >> 4, mm = lane & 15;
        int k = q * 8 + j, n = ct * 16 + mm;
        ws[idx] = (k < 8) ? (bf16_t)SwW[k * HD + n]
                : (k == 8) ? (bf16_t)Swb[n] : (bf16_t)0.f;
    } else if (idx < W_OFF) {
        int t = idx - U_OFF;
        int lg = t >> 12, r2 = t & 4095;
        int l = lg >> 2, g = lg & 3;
        int ct = r2 >> 9, rem = r2 & 511, lane = rem >> 3, j = rem & 7;
        int q = lane >> 4, mm = lane & 15;
        int k = q * 8 + j, n = ct * 16 + mm;
        const float* Bs = (g == 0) ? Bz : (g == 1) ? Bg : (g == 2) ? Br : (const float*)0;
        ws[idx] = (k < 8) ? (bf16_t)Us[g][(l * 8 + k) * HD + n]
                : (k == 8 && g < 3) ? (bf16_t)Bs[l * HD + n] : (bf16_t)0.f;
    } else {
        int t = idx - W_OFF;
        int lg = t >> 14, r2 = t & 16383;
        int l = lg >> 2, g = lg & 3;
        int ct = r2 >> 11, kc = (r2 >> 9) & 3, rem = r2 & 511, lane = rem >> 3, j = rem & 7;
        int q = lane >> 4, mm = lane & 15;
        int k = kc * 32 + q * 8 + j, n = ct * 16 + mm;
        ws[idx] = (bf16_t)Wm[g][(l * HD + k) * HD + n];
    }
}

// ---------------- main: transposed compute, bias-fold, 3 blocks/CU ----------------------------
// Wave ct owns 16 features; thread owns (batch bt*16+m, features f0..f0+3), b64 epilogue writes.
// Phases/layer (2 barriers): P_A(R)->bar ; P_Z ; P_G ; P_H+update ->bar (Z/G/H read LDS stable
// since the barrier, write only own regs / own-column elems). 5 weight frags per phase: fits
// the 85-VGPR cap of (512,6) -> 3 blocks/CU (LDS 53.0 KiB x3 = 159 KiB). red[] lives in the
// dead pad cols (138..139) of s_sig[1], written only during l=2 when nothing reads them.
__global__ __launch_bounds__(THREADS, 6) void dgm_main(
    const float* __restrict__ x,
    const float* __restrict__ Swb,
    const float* __restrict__ Bz, const float* __restrict__ Bg,
    const float* __restrict__ Br, const float* __restrict__ Bh,
    const float* __restrict__ WfW, const float* __restrict__ WfB,
    const bf16_t* __restrict__ ws,
    float* __restrict__ out) {
    __shared__ __align__(16) bf16_t s_sig[2][ROWS * SSTR];  // sigma(S) ping-pong + x + ones
    __shared__ __align__(16) bf16_t s_r[ROWS * RSTR];       // sigma(S)*R + x

    const int tid = threadIdx.x;
    const int lane = tid & 63;
    const int ct = tid >> 6;
    const int m = lane & 15, q = lane >> 4;
    const int rb = blockIdx.x * ROWS;
    const int f0 = ct * 16 + q * 4;
    const int fragoff = (ct * 64 + lane) * 8;
    const int wfragoff = (ct * 4) * 512 + lane * 8;
    const int xoff = 128 + (q ? 8 : 0);   // q=0: x cols; q>0: [1,0..] cols (bias row k=8)

    // stage x into cols 128..135 and the bias-activation vector [1,0,..,0] into 136..143
    {
        int r = tid >> 3, j = tid & 7;
        bf16_t xv = (bf16_t)x[(size_t)(rb + r) * 8 + j];
        s_sig[0][r * SSTR + 128 + j] = xv;
        s_sig[1][r * SSTR + 128 + j] = xv;
        s_r[r * RSTR + 128 + j] = xv;
        bf16_t ov = (j == 0) ? (bf16_t)1.f : (bf16_t)0.f;
        s_sig[0][r * SSTR + 136 + j] = ov;
        s_sig[1][r * SSTR + 136 + j] = ov;
    }
    __syncthreads();

    bf16x4 svp[4];  // sigma(S) at this thread's 16 elements [bt]

    // ---- init: S0^T = Sw'^T @ [x|1]^T  (Swb folded at k=8)
    {
        bf16x8 fSw = *(const bf16x8*)(ws + SW_OFF + fragoff);
#pragma unroll
        for (int bt = 0; bt < 4; bt++) {
            bf16x8 b = *(const bf16x8*)(&s_sig[0][(bt * 16 + m) * SSTR + xoff]);
            f32x4 acc = {0.f, 0.f, 0.f, 0.f};
            acc = MFMA(fSw, b, acc);
            bf16x4 pk;
#pragma unroll
            for (int i = 0; i < 4; i++) pk[i] = (bf16_t)sigm(acc[i]);
            svp[bt] = pk;
            *(bf16x4*)(&s_sig[0][(bt * 16 + m) * SSTR + f0]) = pk;
        }
    }
    __syncthreads();

#pragma unroll 1
    for (int l = 0; l < NL; l++) {
        const int cur = l & 1, nxt = cur ^ 1;
        const bool last = (l == NL - 1);
        const bf16_t* wb = ws + W_OFF + (size_t)l * 4 * 16384;
        const bf16_t* ub = ws + U_OFF + (size_t)l * 4 * 4096;

        // zero the red slots (s_sig[1] pad cols 138..139 as f32) before the last layer's barrier
        if (last && tid < ROWS) *(float*)&s_sig[1][tid * SSTR + 138] = 0.f;

        // ---- P_A: R -> s_r  (Br folded)
        {
            bf16x8 fU = *(const bf16x8*)(ub + 2 * 4096 + fragoff);
            bf16x8 fW[4];
#pragma unroll
            for (int kc = 0; kc < 4; kc++)
                fW[kc] = *(const bf16x8*)(wb + 2 * 16384 + wfragoff + kc * 512);
#pragma unroll
            for (int bt = 0; bt < 4; bt++) {
                const bf16_t* bbase = &s_sig[cur][(bt * 16 + m) * SSTR];
                f32x4 aR = {0.f, 0.f, 0.f, 0.f};
#pragma unroll
                for (int kc = 0; kc < 4; kc++) {
                    bf16x8 b = *(const bf16x8*)(bbase + kc * 32 + q * 8);
                    aR = MFMA(fW[kc], b, aR);
                }
                {
                    bf16x8 b = *(const bf16x8*)(bbase + xoff);   // x|1 chunk
                    aR = MFMA(fU, b, aR);
                }
                bf16x4 pk;
#pragma unroll
                for (int i = 0; i < 4; i++)
                    pk[i] = (bf16_t)(sigm(aR[i]) * (float)svp[bt][i]);
                *(bf16x4*)(&s_r[(bt * 16 + m) * RSTR + f0]) = pk;
            }
        }
        __syncthreads();

        bf16x4 t1p[4];  // z*sigma(S)
        bf16x4 ogp[4];  // 1-G

        // ---- P_Z (Bz folded; regs only)
        {
            bf16x8 fU = *(const bf16x8*)(ub + 0 * 4096 + fragoff);
            bf16x8 fW[4];
#pragma unroll
            for (int kc = 0; kc < 4; kc++)
                fW[kc] = *(const bf16x8*)(wb + 0 * 16384 + wfragoff + kc * 512);
#pragma unroll
            for (int bt = 0; bt < 4; bt++) {
                const bf16_t* bbase = &s_sig[cur][(bt * 16 + m) * SSTR];
                f32x4 aZ = {0.f, 0.f, 0.f, 0.f};
#pragma unroll
                for (int kc = 0; kc < 4; kc++) {
                    bf16x8 b = *(const bf16x8*)(bbase + kc * 32 + q * 8);
                    aZ = MFMA(fW[kc], b, aZ);
                }
                {
                    bf16x8 b = *(const bf16x8*)(bbase + xoff);
                    aZ = MFMA(fU, b, aZ);
                }
                bf16x4 pk;
#pragma unroll
                for (int i = 0; i < 4; i++)
                    pk[i] = (bf16_t)(sigm(aZ[i]) * (float)svp[bt][i]);
                t1p[bt] = pk;
            }
        }

        // ---- P_G (Bg folded; regs only)
        {
            bf16x8 fU = *(const bf16x8*)(ub + 1 * 4096 + fragoff);
            bf16x8 fW[4];
#pragma unroll
            for (int kc = 0; kc < 4; kc++)
                fW[kc] = *(const bf16x8*)(wb + 1 * 16384 + wfragoff + kc * 512);
#pragma unroll
            for (int bt = 0; bt < 4; bt++) {
                const bf16_t* bbase = &s_sig[cur][(bt * 16 + m) * SSTR];
                f32x4 aG = {0.f, 0.f, 0.f, 0.f};
#pragma unroll
                for (int kc = 0; kc < 4; kc++) {
                    bf16x8 b = *(const bf16x8*)(bbase + kc * 32 + q * 8);
                    aG = MFMA(fW[kc], b, aG);
                }
                {
                    bf16x8 b = *(const bf16x8*)(bbase + xoff);
                    aG = MFMA(fU, b, aG);
                }
                bf16x4 pk;
#pragma unroll
                for (int i = 0; i < 4; i++)
                    pk[i] = (bf16_t)sigmn(aG[i]);
                ogp[bt] = pk;
            }
        }

        // ---- P_H + state update (reads s_r; Bh NOT folded — s_r has no 1-col)
        {
            bf16x8 fU = *(const bf16x8*)(ub + 3 * 4096 + fragoff);
            bf16x8 fW[4];
#pragma unroll
            for (int kc = 0; kc < 4; kc++)
                fW[kc] = *(const bf16x8*)(wb + 3 * 16384 + wfragoff + kc * 512);
            const f32x4 bh4 = *(const f32x4*)&Bh[l * HD + f0];
            const f32x4 wf4 = *(const f32x4*)&WfW[f0];
#pragma unroll
            for (int bt = 0; bt < 4; bt++) {
                const bf16_t* bbase = &s_r[(bt * 16 + m) * RSTR];
                f32x4 aH = {0.f, 0.f, 0.f, 0.f};
#pragma unroll
                for (int kc = 0; kc < 4; kc++) {
                    bf16x8 b = *(const bf16x8*)(bbase + kc * 32 + q * 8);
                    aH = MFMA(fW[kc], b, aH);
                }
                {
                    bf16x8 b = *(const bf16x8*)(bbase + 128);    // x chunk (all quads; Uh rows 8+ = 0)
                    aH = MFMA(fU, b, aH);
                }
                if (last) {
                    float p = 0.f;
#pragma unroll
                    for (int i = 0; i < 4; i++) {
                        float hh = tanh_f(aH[i] + bh4[i]);
                        float sn = (float)ogp[bt][i] * hh + (float)t1p[bt][i];
                        p += sn * wf4[i];              // fold S3@Wf; S3 stays f32
                    }
                    p += __shfl_xor(p, 16);            // sum over q
                    p += __shfl_xor(p, 32);
                    if (q == 0)
                        atomicAdd((float*)&s_sig[1][(bt * 16 + m) * SSTR + 138], p);
                } else {
                    bf16x4 pk;
#pragma unroll
                    for (int i = 0; i < 4; i++) {
                        float hh = tanh_f(aH[i] + bh4[i]);
                        float sn = (float)ogp[bt][i] * hh + (float)t1p[bt][i];
                        pk[i] = (bf16_t)sigm(sn);
                    }
                    svp[bt] = pk;
                    *(bf16x4*)(&s_sig[nxt][(bt * 16 + m) * SSTR + f0]) = pk;
                }
            }
        }
        __syncthreads();
    }

    if (tid < ROWS) out[rb + tid] = *(const float*)&s_sig[1][tid * SSTR + 138] + WfB[0];
}

extern "C" void kernel_launch(void* const* d_in, const int* in_sizes, int n_in,
                              void* d_out, int out_size, void* d_ws, size_t ws_size,
                              hipStream_t stream) {
    const float* x   = (const float*)d_in[0];
    const float* SwW = (const float*)d_in[1];
    const float* Swb = (const float*)d_in[2];
    const float* Uz  = (const float*)d_in[3];
    const float* Wz  = (const float*)d_in[4];
    const float* Bz  = (const float*)d_in[5];
    const float* Ug  = (const float*)d_in[6];
    const float* Wg  = (const float*)d_in[7];
    const float* Bg  = (const float*)d_in[8];
    const float* Ur  = (const float*)d_in[9];
    const float* Wr  = (const float*)d_in[10];
    const float* Br  = (const float*)d_in[11];
    const float* Uh  = (const float*)d_in[12];
    const float* Wh  = (const float*)d_in[13];
    const float* Bh  = (const float*)d_in[14];
    const float* WfW = (const float*)d_in[15];
    const float* WfB = (const float*)d_in[16];
    bf16_t* ws = (bf16_t*)d_ws;
    float* out = (float*)d_out;

    if (ws_size < (size_t)WS_ELEMS * sizeof(bf16_t)) return;

    dgm_prep<<<(WS_ELEMS + 255) / 256, 256, 0, stream>>>(SwW, Swb, Uz, Wz, Bz, Ug, Wg, Bg,
                                                         Ur, Wr, Br, Uh, Wh, ws);
    dgm_main<<<NBLK, THREADS, 0, stream>>>(x, Swb, Bz, Bg, Br, Bh, WfW, WfB, ws, out);
}

// Round 14
// 273.478 us; speedup vs baseline: 1.5662x; 1.5662x over previous
//
#include <hip/hip_runtime.h>

typedef __bf16 bf16_t;
typedef __bf16 bf16x4 __attribute__((ext_vector_type(4)));
typedef __bf16 bf16x8 __attribute__((ext_vector_type(8)));
typedef float f32x4 __attribute__((ext_vector_type(4)));

#define NL 3
#define HD 128
#define ROWS 64
#define SSTR 144         // s_sig stride: 128 data + x(128..135) + [1,0..0](136..143) bias-fold cols
#define RSTR 136         // s_r stride: 128 data + x(128..135)
#define THREADS 512
#define BATCH 262144
#define NBLK (BATCH / ROWS)

// ws layout (bf16 elems): MFMA fragment order; U sections carry bias at k==8 (Sw, z, g, r)
#define SW_OFF 0                 // [ct=8][lane=64][j=8]                       = 4096
#define U_OFF  4096              // [l=3][g=4][ct=8][lane=64][j=8]             = 49152
#define W_OFF  53248             // [l=3][g=4][ct=8][kc=4][lane=64][j=8]       = 196608
#define WS_ELEMS 249856

#define MFMA(a, b, c) __builtin_amdgcn_mfma_f32_16x16x32_bf16((a), (b), (c), 0, 0, 0)

#define LOG2E 1.4426950408889634f
__device__ __forceinline__ float sigm(float v) {
    return __builtin_amdgcn_rcpf(1.f + __builtin_amdgcn_exp2f(-LOG2E * v));
}
__device__ __forceinline__ float sigmn(float v) {  // 1 - sigm(v)
    return __builtin_amdgcn_rcpf(1.f + __builtin_amdgcn_exp2f(LOG2E * v));
}
__device__ __forceinline__ float tanh_f(float v) {
    return 1.f - 2.f * __builtin_amdgcn_rcpf(__builtin_amdgcn_exp2f((2.f * LOG2E) * v) + 1.f);
}

// ---------------- prep: swizzle f32 weights (+ biases at k==8) into bf16 fragment order -------
__global__ void dgm_prep(const float* __restrict__ SwW, const float* __restrict__ Swb,
                         const float* __restrict__ Uz, const float* __restrict__ Wz, const float* __restrict__ Bz,
                         const float* __restrict__ Ug, const float* __restrict__ Wg, const float* __restrict__ Bg,
                         const float* __restrict__ Ur, const float* __restrict__ Wr, const float* __restrict__ Br,
                         const float* __restrict__ Uh, const float* __restrict__ Wh,
                         bf16_t* __restrict__ ws) {
    int idx = blockIdx.x * 256 + threadIdx.x;
    if (idx >= WS_ELEMS) return;
    const float* Us[4] = {Uz, Ug, Ur, Uh};
    const float* Wm[4] = {Wz, Wg, Wr, Wh};
    if (idx < U_OFF) {
        int ct = idx >> 9, rem = idx & 511, lane = rem >> 3, j = rem & 7;
        int q = lane >> 4, mm = lane & 15;
        int k = q * 8 + j, n = ct * 16 + mm;
        ws[idx] = (k < 8) ? (bf16_t)SwW[k * HD + n]
                : (k == 8) ? (bf16_t)Swb[n] : (bf16_t)0.f;
    } else if (idx < W_OFF) {
        int t = idx - U_OFF;
        int lg = t >> 12, r2 = t & 4095;
        int l = lg >> 2, g = lg & 3;
        int ct = r2 >> 9, rem = r2 & 511, lane = rem >> 3, j = rem & 7;
        int q = lane >> 4, mm = lane & 15;
        int k = q * 8 + j, n = ct * 16 + mm;
        const float* Bs = (g == 0) ? Bz : (g == 1) ? Bg : (g == 2) ? Br : (const float*)0;
        ws[idx] = (k < 8) ? (bf16_t)Us[g][(l * 8 + k) * HD + n]
                : (k == 8 && g < 3) ? (bf16_t)Bs[l * HD + n] : (bf16_t)0.f;
    } else {
        int t = idx - W_OFF;
        int lg = t >> 14, r2 = t & 16383;
        int l = lg >> 2, g = lg & 3;
        int ct = r2 >> 11, kc = (r2 >> 9) & 3, rem = r2 & 511, lane = rem >> 3, j = rem & 7;
        int q = lane >> 4, mm = lane & 15;
        int k = kc * 32 + q * 8 + j, n = ct * 16 + mm;
        ws[idx] = (bf16_t)Wm[g][(l * HD + k) * HD + n];
    }
}

// ---------------- main: transposed compute + bias-fold, (512,4) ------------------------------
// r12 phase structure (P_A(R)->bar ; P_ZG fused ; P_H+update ->bar) with Swb/Bz/Bg/Br folded
// into the augmented K chunk: quads q>=1 read the [1,0..0] cols (136..143) so A-row k=8 (bias)
// meets B=1. r12's 62 MB spill was the 20 live bias/Wf regs; folding removes 12 of them ->
// expect r9-like no-spill at the 128-unified budget of (512,4). Bh/Wf stay in the P_H epilogue.
__global__ __launch_bounds__(THREADS, 4) void dgm_main(
    const float* __restrict__ x,
    const float* __restrict__ Bh,
    const float* __restrict__ WfW, const float* __restrict__ WfB,
    const bf16_t* __restrict__ ws,
    float* __restrict__ out) {
    __shared__ __align__(16) bf16_t s_sig[2][ROWS * SSTR];  // sigma(S) ping-pong + x + [1,0..]
    __shared__ __align__(16) bf16_t s_r[ROWS * RSTR];       // sigma(S)*R + x
    __shared__ float red[ROWS];

    const int tid = threadIdx.x;
    const int lane = tid & 63;
    const int ct = tid >> 6;
    const int m = lane & 15, q = lane >> 4;
    const int rb = blockIdx.x * ROWS;
    const int f0 = ct * 16 + q * 4;
    const int fragoff = (ct * 64 + lane) * 8;
    const int wfragoff = (ct * 4) * 512 + lane * 8;
    const int xoff = 128 + (q ? 8 : 0);   // q=0: x cols; q>=1: [1,0..] cols (A rows k>8 are 0)

    if (tid < ROWS) red[tid] = 0.f;

    // stage x into cols 128..135 and [1,0,..,0] into 136..143
    {
        int r = tid >> 3, j = tid & 7;
        bf16_t xv = (bf16_t)x[(size_t)(rb + r) * 8 + j];
        s_sig[0][r * SSTR + 128 + j] = xv;
        s_sig[1][r * SSTR + 128 + j] = xv;
        s_r[r * RSTR + 128 + j] = xv;
        bf16_t ov = (j == 0) ? (bf16_t)1.f : (bf16_t)0.f;
        s_sig[0][r * SSTR + 136 + j] = ov;
        s_sig[1][r * SSTR + 136 + j] = ov;
    }
    __syncthreads();

    bf16x4 svp[4];  // sigma(S) at this thread's 16 elements [bt]

    // ---- init: S0^T = Sw'^T @ [x|1]^T  (Swb folded at k=8)
    {
        bf16x8 fSw = *(const bf16x8*)(ws + SW_OFF + fragoff);
#pragma unroll
        for (int bt = 0; bt < 4; bt++) {
            bf16x8 b = *(const bf16x8*)(&s_sig[0][(bt * 16 + m) * SSTR + xoff]);
            f32x4 acc = {0.f, 0.f, 0.f, 0.f};
            acc = MFMA(fSw, b, acc);
            bf16x4 pk;
#pragma unroll
            for (int i = 0; i < 4; i++) pk[i] = (bf16_t)sigm(acc[i]);
            svp[bt] = pk;
            *(bf16x4*)(&s_sig[0][(bt * 16 + m) * SSTR + f0]) = pk;
        }
    }
    __syncthreads();

#pragma unroll 1
    for (int l = 0; l < NL; l++) {
        const int cur = l & 1, nxt = cur ^ 1;
        const bool last = (l == NL - 1);
        const bf16_t* wb = ws + W_OFF + (size_t)l * 4 * 16384;
        const bf16_t* ub = ws + U_OFF + (size_t)l * 4 * 4096;

        // ---- P_A: R -> s_r  (Br folded)
        {
            bf16x8 fU = *(const bf16x8*)(ub + 2 * 4096 + fragoff);
            bf16x8 fW[4];
#pragma unroll
            for (int kc = 0; kc < 4; kc++)
                fW[kc] = *(const bf16x8*)(wb + 2 * 16384 + wfragoff + kc * 512);
#pragma unroll
            for (int bt = 0; bt < 4; bt++) {
                const bf16_t* bbase = &s_sig[cur][(bt * 16 + m) * SSTR];
                f32x4 aR = {0.f, 0.f, 0.f, 0.f};
#pragma unroll
                for (int kc = 0; kc < 4; kc++) {
                    bf16x8 b = *(const bf16x8*)(bbase + kc * 32 + q * 8);
                    aR = MFMA(fW[kc], b, aR);
                }
                {
                    bf16x8 b = *(const bf16x8*)(bbase + xoff);   // x|1 chunk
                    aR = MFMA(fU, b, aR);
                }
                bf16x4 pk;
#pragma unroll
                for (int i = 0; i < 4; i++)
                    pk[i] = (bf16_t)(sigm(aR[i]) * (float)svp[bt][i]);
                *(bf16x4*)(&s_r[(bt * 16 + m) * RSTR + f0]) = pk;
            }
        }
        __syncthreads();

        bf16x4 t1p[4];  // z*sigma(S)
        bf16x4 ogp[4];  // 1-G

        // ---- P_ZG: Z and G share each B-fragment read (Bz/Bg folded; regs only)
        {
            bf16x8 fUz = *(const bf16x8*)(ub + 0 * 4096 + fragoff);
            bf16x8 fUg = *(const bf16x8*)(ub + 1 * 4096 + fragoff);
            bf16x8 fWz[4], fWg[4];
#pragma unroll
            for (int kc = 0; kc < 4; kc++) {
                fWz[kc] = *(const bf16x8*)(wb + 0 * 16384 + wfragoff + kc * 512);
                fWg[kc] = *(const bf16x8*)(wb + 1 * 16384 + wfragoff + kc * 512);
            }
#pragma unroll
            for (int bt = 0; bt < 4; bt++) {
                const bf16_t* bbase = &s_sig[cur][(bt * 16 + m) * SSTR];
                f32x4 aZ = {0.f, 0.f, 0.f, 0.f}, aG = {0.f, 0.f, 0.f, 0.f};
#pragma unroll
                for (int kc = 0; kc < 4; kc++) {
                    bf16x8 b = *(const bf16x8*)(bbase + kc * 32 + q * 8);
                    aZ = MFMA(fWz[kc], b, aZ);
                    aG = MFMA(fWg[kc], b, aG);
                }
                {
                    bf16x8 b = *(const bf16x8*)(bbase + xoff);   // x|1 chunk
                    aZ = MFMA(fUz, b, aZ);
                    aG = MFMA(fUg, b, aG);
                }
                bf16x4 t1, og;
#pragma unroll
                for (int i = 0; i < 4; i++) {
                    t1[i] = (bf16_t)(sigm(aZ[i]) * (float)svp[bt][i]);
                    og[i] = (bf16_t)sigmn(aG[i]);
                }
                t1p[bt] = t1;
                ogp[bt] = og;
            }
        }

        // ---- P_H + state update (reads s_r, stable since P_A's barrier; Bh/Wf in epilogue)
        {
            bf16x8 fU = *(const bf16x8*)(ub + 3 * 4096 + fragoff);
            bf16x8 fW[4];
#pragma unroll
            for (int kc = 0; kc < 4; kc++)
                fW[kc] = *(const bf16x8*)(wb + 3 * 16384 + wfragoff + kc * 512);
            const f32x4 bh4 = *(const f32x4*)&Bh[l * HD + f0];
#pragma unroll
            for (int bt = 0; bt < 4; bt++) {
                const bf16_t* bbase = &s_r[(bt * 16 + m) * RSTR];
                f32x4 aH = {0.f, 0.f, 0.f, 0.f};
#pragma unroll
                for (int kc = 0; kc < 4; kc++) {
                    bf16x8 b = *(const bf16x8*)(bbase + kc * 32 + q * 8);
                    aH = MFMA(fW[kc], b, aH);
                }
                {
                    bf16x8 b = *(const bf16x8*)(bbase + 128);    // x chunk (Uh rows 8+ are 0)
                    aH = MFMA(fU, b, aH);
                }
                if (last) {
                    const f32x4 wf4 = *(const f32x4*)&WfW[f0];
                    float p = 0.f;
#pragma unroll
                    for (int i = 0; i < 4; i++) {
                        float hh = tanh_f(aH[i] + bh4[i]);
                        float sn = (float)ogp[bt][i] * hh + (float)t1p[bt][i];
                        p += sn * wf4[i];              // fold S3@Wf; S3 stays f32
                    }
                    p += __shfl_xor(p, 16);            // sum over q (features)
                    p += __shfl_xor(p, 32);
                    if (q == 0) atomicAdd(&red[bt * 16 + m], p);
                } else {
                    bf16x4 pk;
#pragma unroll
                    for (int i = 0; i < 4; i++) {
                        float hh = tanh_f(aH[i] + bh4[i]);
                        float sn = (float)ogp[bt][i] * hh + (float)t1p[bt][i];
                        pk[i] = (bf16_t)sigm(sn);
                    }
                    svp[bt] = pk;
                    *(bf16x4*)(&s_sig[nxt][(bt * 16 + m) * SSTR + f0]) = pk;
                }
            }
        }
        __syncthreads();
    }

    if (tid < ROWS) out[rb + tid] = red[tid] + WfB[0];
}

extern "C" void kernel_launch(void* const* d_in, const int* in_sizes, int n_in,
                              void* d_out, int out_size, void* d_ws, size_t ws_size,
                              hipStream_t stream) {
    const float* x   = (const float*)d_in[0];
    const float* SwW = (const float*)d_in[1];
    const float* Swb = (const float*)d_in[2];
    const float* Uz  = (const float*)d_in[3];
    const float* Wz  = (const float*)d_in[4];
    const float* Bz  = (const float*)d_in[5];
    const float* Ug  = (const float*)d_in[6];
    const float* Wg  = (const float*)d_in[7];
    const float* Bg  = (const float*)d_in[8];
    const float* Ur  = (const float*)d_in[9];
    const float* Wr  = (const float*)d_in[10];
    const float* Br  = (const float*)d_in[11];
    const float* Uh  = (const float*)d_in[12];
    const float* Wh  = (const float*)d_in[13];
    const float* Bh  = (const float*)d_in[14];
    const float* WfW = (const float*)d_in[15];
    const float* WfB = (const float*)d_in[16];
    bf16_t* ws = (bf16_t*)d_ws;
    float* out = (float*)d_out;

    if (ws_size < (size_t)WS_ELEMS * sizeof(bf16_t)) return;

    dgm_prep<<<(WS_ELEMS + 255) / 256, 256, 0, stream>>>(SwW, Swb, Uz, Wz, Bz, Ug, Wg, Bg,
                                                         Ur, Wr, Br, Uh, Wh, ws);
    dgm_main<<<NBLK, THREADS, 0, stream>>>(x, Bh, WfW, WfB, ws, out);
}

// Round 15
// 269.502 us; speedup vs baseline: 1.5893x; 1.0148x over previous
//
#include <hip/hip_runtime.h>

typedef __bf16 bf16_t;
typedef __bf16 bf16x4 __attribute__((ext_vector_type(4)));
typedef __bf16 bf16x8 __attribute__((ext_vector_type(8)));
typedef float f32x4 __attribute__((ext_vector_type(4)));

#define NL 3
#define HD 128
#define ROWS 64
#define SSTR 152         // 128 data + x(128..135) + [1,0..](136..143) + dead(144..151); 304B=12 dw mod 32 -> 2-way banks
#define RSTR 136         // s_r: 128 data + x(128..135); 272B=4 dw mod 32 -> 2-way banks
#define THREADS 512
#define BATCH 262144
#define NBLK (BATCH / ROWS)

// ws layout (bf16 elems): MFMA fragment order; biases folded at k==8; activation constants
// pre-multiplied into the weights: Sw,z,r x(-LOG2E); g x(+LOG2E) [gives 1-G]; h x(2*LOG2E).
#define SW_OFF 0                 // [ct=8][lane=64][j=8]                       = 4096
#define U_OFF  4096              // [l=3][g=4][ct=8][lane=64][j=8]             = 49152
#define W_OFF  53248             // [l=3][g=4][ct=8][kc=4][lane=64][j=8]       = 196608
#define WS_ELEMS 249856

#define MFMA(a, b, c) __builtin_amdgcn_mfma_f32_16x16x32_bf16((a), (b), (c), 0, 0, 0)

#define LOG2E 1.4426950408889634f
// activations on PRE-SCALED accumulators (no input multiply):
__device__ __forceinline__ float sige(float a) {   // = sigm(v) for a=-LOG2E*v ; = 1-sigm(v) for a=+LOG2E*v
    return __builtin_amdgcn_rcpf(1.f + __builtin_amdgcn_exp2f(a));
}
__device__ __forceinline__ float tanhe(float a) {  // = tanh(v) for a=2*LOG2E*v
    return 1.f - 2.f * __builtin_amdgcn_rcpf(__builtin_amdgcn_exp2f(a) + 1.f);
}
__device__ __forceinline__ float sigm(float v) {   // full sigmoid (for sigma(S_next))
    return __builtin_amdgcn_rcpf(1.f + __builtin_amdgcn_exp2f(-LOG2E * v));
}

// ---------------- prep: swizzle f32 weights (+bias k==8, pre-scaled) into bf16 frag order ----
__global__ void dgm_prep(const float* __restrict__ SwW, const float* __restrict__ Swb,
                         const float* __restrict__ Uz, const float* __restrict__ Wz, const float* __restrict__ Bz,
                         const float* __restrict__ Ug, const float* __restrict__ Wg, const float* __restrict__ Bg,
                         const float* __restrict__ Ur, const float* __restrict__ Wr, const float* __restrict__ Br,
                         const float* __restrict__ Uh, const float* __restrict__ Wh,
                         bf16_t* __restrict__ ws) {
    int idx = blockIdx.x * 256 + threadIdx.x;
    if (idx >= WS_ELEMS) return;
    const float* Us[4] = {Uz, Ug, Ur, Uh};
    const float* Wm[4] = {Wz, Wg, Wr, Wh};
    const float gsc[4] = {-LOG2E, LOG2E, -LOG2E, 2.f * LOG2E};  // z, g, r, h
    if (idx < U_OFF) {
        int ct = idx >> 9, rem = idx & 511, lane = rem >> 3, j = rem & 7;
        int q = lane >> 4, mm = lane & 15;
        int k = q * 8 + j, n = ct * 16 + mm;
        float v = (k < 8) ? SwW[k * HD + n] : (k == 8) ? Swb[n] : 0.f;
        ws[idx] = (bf16_t)(v * -LOG2E);
    } else if (idx < W_OFF) {
        int t = idx - U_OFF;
        int lg = t >> 12, r2 = t & 4095;
        int l = lg >> 2, g = lg & 3;
        int ct = r2 >> 9, rem = r2 & 511, lane = rem >> 3, j = rem & 7;
        int q = lane >> 4, mm = lane & 15;
        int k = q * 8 + j, n = ct * 16 + mm;
        const float* Bs = (g == 0) ? Bz : (g == 1) ? Bg : (g == 2) ? Br : (const float*)0;
        float v = (k < 8) ? Us[g][(l * 8 + k) * HD + n]
                : (k == 8 && g < 3) ? Bs[l * HD + n] : 0.f;
        ws[idx] = (bf16_t)(v * gsc[g]);
    } else {
        int t = idx - W_OFF;
        int lg = t >> 14, r2 = t & 16383;
        int l = lg >> 2, g = lg & 3;
        int ct = r2 >> 11, kc = (r2 >> 9) & 3, rem = r2 & 511, lane = rem >> 3, j = rem & 7;
        int q = lane >> 4, mm = lane & 15;
        int k = kc * 32 + q * 8 + j, n = ct * 16 + mm;
        ws[idx] = (bf16_t)(Wm[g][(l * HD + k) * HD + n] * gsc[g]);
    }
}

// ---------------- main: transposed compute + bias-fold + prescaled activations, (512,4) ------
__global__ __launch_bounds__(THREADS, 4) void dgm_main(
    const float* __restrict__ x,
    const float* __restrict__ Bh,
    const float* __restrict__ WfW, const float* __restrict__ WfB,
    const bf16_t* __restrict__ ws,
    float* __restrict__ out) {
    __shared__ __align__(16) bf16_t s_sig[2][ROWS * SSTR];  // sigma(S) ping-pong + x + [1,0..]
    __shared__ __align__(16) bf16_t s_r[ROWS * RSTR];       // sigma(S)*R + x
    __shared__ float red[ROWS];

    const int tid = threadIdx.x;
    const int lane = tid & 63;
    const int ct = tid >> 6;
    const int m = lane & 15, q = lane >> 4;
    const int rb = blockIdx.x * ROWS;
    const int f0 = ct * 16 + q * 4;
    const int fragoff = (ct * 64 + lane) * 8;
    const int wfragoff = (ct * 4) * 512 + lane * 8;
    const int xoff = 128 + (q ? 8 : 0);   // q=0: x cols; q>=1: [1,0..] cols (A rows k>8 are 0)

    if (tid < ROWS) red[tid] = 0.f;

    // stage x into cols 128..135 and [1,0,..,0] into 136..143 (cols 144..151 dead, never read)
    {
        int r = tid >> 3, j = tid & 7;
        bf16_t xv = (bf16_t)x[(size_t)(rb + r) * 8 + j];
        s_sig[0][r * SSTR + 128 + j] = xv;
        s_sig[1][r * SSTR + 128 + j] = xv;
        s_r[r * RSTR + 128 + j] = xv;
        bf16_t ov = (j == 0) ? (bf16_t)1.f : (bf16_t)0.f;
        s_sig[0][r * SSTR + 136 + j] = ov;
        s_sig[1][r * SSTR + 136 + j] = ov;
    }
    __syncthreads();

    bf16x4 svp[4];  // sigma(S) at this thread's 16 elements [bt]

    // ---- init: acc = -LOG2E*(x@Sw + b) ; sigma = sige(acc)
    {
        bf16x8 fSw = *(const bf16x8*)(ws + SW_OFF + fragoff);
#pragma unroll
        for (int bt = 0; bt < 4; bt++) {
            bf16x8 b = *(const bf16x8*)(&s_sig[0][(bt * 16 + m) * SSTR + xoff]);
            f32x4 acc = {0.f, 0.f, 0.f, 0.f};
            acc = MFMA(fSw, b, acc);
            bf16x4 pk;
#pragma unroll
            for (int i = 0; i < 4; i++) pk[i] = (bf16_t)sige(acc[i]);
            svp[bt] = pk;
            *(bf16x4*)(&s_sig[0][(bt * 16 + m) * SSTR + f0]) = pk;
        }
    }
    __syncthreads();

#pragma unroll 1
    for (int l = 0; l < NL; l++) {
        const int cur = l & 1, nxt = cur ^ 1;
        const bool last = (l == NL - 1);
        const bf16_t* wb = ws + W_OFF + (size_t)l * 4 * 16384;
        const bf16_t* ub = ws + U_OFF + (size_t)l * 4 * 4096;

        // ---- P_A: R -> s_r  (Br folded, -LOG2E prescaled)
        {
            bf16x8 fU = *(const bf16x8*)(ub + 2 * 4096 + fragoff);
            bf16x8 fW[4];
#pragma unroll
            for (int kc = 0; kc < 4; kc++)
                fW[kc] = *(const bf16x8*)(wb + 2 * 16384 + wfragoff + kc * 512);
#pragma unroll
            for (int bt = 0; bt < 4; bt++) {
                const bf16_t* bbase = &s_sig[cur][(bt * 16 + m) * SSTR];
                f32x4 aR = {0.f, 0.f, 0.f, 0.f};
#pragma unroll
                for (int kc = 0; kc < 4; kc++) {
                    bf16x8 b = *(const bf16x8*)(bbase + kc * 32 + q * 8);
                    aR = MFMA(fW[kc], b, aR);
                }
                {
                    bf16x8 b = *(const bf16x8*)(bbase + xoff);   // x|1 chunk
                    aR = MFMA(fU, b, aR);
                }
                bf16x4 pk;
#pragma unroll
                for (int i = 0; i < 4; i++)
                    pk[i] = (bf16_t)(sige(aR[i]) * (float)svp[bt][i]);
                *(bf16x4*)(&s_r[(bt * 16 + m) * RSTR + f0]) = pk;
            }
        }
        __syncthreads();

        bf16x4 t1p[4];  // z*sigma(S)
        bf16x4 ogp[4];  // 1-G

        // ---- P_ZG: Z and G share each B-fragment read (Bz/Bg folded; G prescaled +LOG2E -> sige gives 1-G)
        {
            bf16x8 fUz = *(const bf16x8*)(ub + 0 * 4096 + fragoff);
            bf16x8 fUg = *(const bf16x8*)(ub + 1 * 4096 + fragoff);
            bf16x8 fWz[4], fWg[4];
#pragma unroll
            for (int kc = 0; kc < 4; kc++) {
                fWz[kc] = *(const bf16x8*)(wb + 0 * 16384 + wfragoff + kc * 512);
                fWg[kc] = *(const bf16x8*)(wb + 1 * 16384 + wfragoff + kc * 512);
            }
#pragma unroll
            for (int bt = 0; bt < 4; bt++) {
                const bf16_t* bbase = &s_sig[cur][(bt * 16 + m) * SSTR];
                f32x4 aZ = {0.f, 0.f, 0.f, 0.f}, aG = {0.f, 0.f, 0.f, 0.f};
#pragma unroll
                for (int kc = 0; kc < 4; kc++) {
                    bf16x8 b = *(const bf16x8*)(bbase + kc * 32 + q * 8);
                    aZ = MFMA(fWz[kc], b, aZ);
                    aG = MFMA(fWg[kc], b, aG);
                }
                {
                    bf16x8 b = *(const bf16x8*)(bbase + xoff);   // x|1 chunk
                    aZ = MFMA(fUz, b, aZ);
                    aG = MFMA(fUg, b, aG);
                }
                bf16x4 t1, og;
#pragma unroll
                for (int i = 0; i < 4; i++) {
                    t1[i] = (bf16_t)(sige(aZ[i]) * (float)svp[bt][i]);
                    og[i] = (bf16_t)sige(aG[i]);
                }
                t1p[bt] = t1;
                ogp[bt] = og;
            }
        }

        // ---- P_H + state update (reads s_r; Wh/Uh prescaled 2*LOG2E; bh scaled at load)
        {
            bf16x8 fU = *(const bf16x8*)(ub + 3 * 4096 + fragoff);
            bf16x8 fW[4];
#pragma unroll
            for (int kc = 0; kc < 4; kc++)
                fW[kc] = *(const bf16x8*)(wb + 3 * 16384 + wfragoff + kc * 512);
            f32x4 bh4 = *(const f32x4*)&Bh[l * HD + f0];
#pragma unroll
            for (int i = 0; i < 4; i++) bh4[i] *= 2.f * LOG2E;
#pragma unroll
            for (int bt = 0; bt < 4; bt++) {
                const bf16_t* bbase = &s_r[(bt * 16 + m) * RSTR];
                f32x4 aH = {0.f, 0.f, 0.f, 0.f};
#pragma unroll
                for (int kc = 0; kc < 4; kc++) {
                    bf16x8 b = *(const bf16x8*)(bbase + kc * 32 + q * 8);
                    aH = MFMA(fW[kc], b, aH);
                }
                {
                    bf16x8 b = *(const bf16x8*)(bbase + 128);    // x chunk (Uh rows 8+ are 0)
                    aH = MFMA(fU, b, aH);
                }
                if (last) {
                    const f32x4 wf4 = *(const f32x4*)&WfW[f0];
                    float p = 0.f;
#pragma unroll
                    for (int i = 0; i < 4; i++) {
                        float hh = tanhe(aH[i] + bh4[i]);
                        float sn = (float)ogp[bt][i] * hh + (float)t1p[bt][i];
                        p += sn * wf4[i];              // fold S3@Wf; S3 stays f32
                    }
                    p += __shfl_xor(p, 16);            // sum over q (features)
                    p += __shfl_xor(p, 32);
                    if (q == 0) atomicAdd(&red[bt * 16 + m], p);
                } else {
                    bf16x4 pk;
#pragma unroll
                    for (int i = 0; i < 4; i++) {
                        float hh = tanhe(aH[i] + bh4[i]);
                        float sn = (float)ogp[bt][i] * hh + (float)t1p[bt][i];
                        pk[i] = (bf16_t)sigm(sn);
                    }
                    svp[bt] = pk;
                    *(bf16x4*)(&s_sig[nxt][(bt * 16 + m) * SSTR + f0]) = pk;
                }
            }
        }
        __syncthreads();
    }

    if (tid < ROWS) out[rb + tid] = red[tid] + WfB[0];
}

extern "C" void kernel_launch(void* const* d_in, const int* in_sizes, int n_in,
                              void* d_out, int out_size, void* d_ws, size_t ws_size,
                              hipStream_t stream) {
    const float* x   = (const float*)d_in[0];
    const float* SwW = (const float*)d_in[1];
    const float* Swb = (const float*)d_in[2];
    const float* Uz  = (const float*)d_in[3];
    const float* Wz  = (const float*)d_in[4];
    const float* Bz  = (const float*)d_in[5];
    const float* Ug  = (const float*)d_in[6];
    const float* Wg  = (const float*)d_in[7];
    const float* Bg  = (const float*)d_in[8];
    const float* Ur  = (const float*)d_in[9];
    const float* Wr  = (const float*)d_in[10];
    const float* Br  = (const float*)d_in[11];
    const float* Uh  = (const float*)d_in[12];
    const float* Wh  = (const float*)d_in[13];
    const float* Bh  = (const float*)d_in[14];
    const float* WfW = (const float*)d_in[15];
    const float* WfB = (const float*)d_in[16];
    bf16_t* ws = (bf16_t*)d_ws;
    float* out = (float*)d_out;

    if (ws_size < (size_t)WS_ELEMS * sizeof(bf16_t)) return;

    dgm_prep<<<(WS_ELEMS + 255) / 256, 256, 0, stream>>>(SwW, Swb, Uz, Wz, Bz, Ug, Wg, Bg,
                                                         Ur, Wr, Br, Uh, Wh, ws);
    dgm_main<<<NBLK, THREADS, 0, stream>>>(x, Bh, WfW, WfB, ws, out);
}